// Round 6
// baseline (426.657 us; speedup 1.0000x reference)
//
#include <hip/hip_runtime.h>

#define S_SCALE 30.0f
#define COS_M 0.8775825618903728f
#define SIN_M 0.479425538604203f
#define TH_C (-0.8775825618903728f)
#define MM_C 0.2397127693021015f

#define BD 512
#define DD 512
#define CC 100000
#define NCB2 782            // ceil(100000/128) col-blocks
#define LASTB2 781
#define NPART 1564          // 782 col-blocks x 2 col-groups of 64
#define CPAD 100096         // 782*128 padded col count

typedef __bf16 bf16x8 __attribute__((ext_vector_type(8)));
typedef __bf16 bf16x4 __attribute__((ext_vector_type(4)));
typedef float  f32x4  __attribute__((ext_vector_type(4)));

#define AS1 __attribute__((address_space(1)))
#define AS3 __attribute__((address_space(3)))

// ---------------- Kernel 1 (merged): blocks 0..127: concat+normalize -> k-tiled
// bf16 At[16][512][32] + label-column cosine/phi.  Blocks 128..909: W -> bf16
// k-tiled Wt[782][16][128][32] + per-column sumsq csqg (on bf16-truncated values).
__global__ __launch_bounds__(256) void k_prep(const float* __restrict__ img,
                                              const float* __restrict__ prof,
                                              const float* __restrict__ W,
                                              const int* __restrict__ lab,
                                              __bf16* __restrict__ At,
                                              float* __restrict__ sphi,
                                              float* __restrict__ scos,
                                              __bf16* __restrict__ Wt,
                                              float* __restrict__ csqg,
                                              int* __restrict__ cnt) {
    const int t = threadIdx.x;
    const int wave = t >> 6, l = t & 63;

    if (blockIdx.x < 128) {
        // ---------- A-prep (one wave per row) ----------
        if (blockIdx.x == 0 && t == 0) cnt[0] = 0;   // reset ticket for k_reduce
        const int row = blockIdx.x * 4 + wave;
        const float* src = (row < 256) ? (img + (size_t)row * DD)
                                       : (prof + (size_t)(row - 256) * DD);
        float4 v0 = ((const float4*)src)[l * 2];
        float4 v1 = ((const float4*)src)[l * 2 + 1];
        float s = v0.x * v0.x + v0.y * v0.y + v0.z * v0.z + v0.w * v0.w
                + v1.x * v1.x + v1.y * v1.y + v1.z * v1.z + v1.w * v1.w;
        #pragma unroll
        for (int o = 1; o < 64; o <<= 1) s += __shfl_xor(s, o);
        float r = rsqrtf(s);
        bf16x8 a;
        a[0] = (__bf16)(v0.x * r); a[1] = (__bf16)(v0.y * r);
        a[2] = (__bf16)(v0.z * r); a[3] = (__bf16)(v0.w * r);
        a[4] = (__bf16)(v1.x * r); a[5] = (__bf16)(v1.y * r);
        a[6] = (__bf16)(v1.z * r); a[7] = (__bf16)(v1.w * r);
        // element (row, d) -> At[(d>>5)*16384 + row*32 + (d&31)]
        *(bf16x8*)(At + (size_t)(l >> 2) * (BD * 32) + row * 32 + (l & 3) * 8) = a;

        // label-column cosine (bf16-truncated, matching the GEMM)
        const int c = lab[row & 255];
        const float4* wc = (const float4*)(W + (size_t)c * DD);
        float4 w0 = wc[l * 2], w1 = wc[l * 2 + 1];
        float wb0 = (float)(__bf16)w0.x, wb1 = (float)(__bf16)w0.y;
        float wb2 = (float)(__bf16)w0.z, wb3 = (float)(__bf16)w0.w;
        float wb4 = (float)(__bf16)w1.x, wb5 = (float)(__bf16)w1.y;
        float wb6 = (float)(__bf16)w1.z, wb7 = (float)(__bf16)w1.w;
        float dot = (float)a[0] * wb0 + (float)a[1] * wb1 + (float)a[2] * wb2
                  + (float)a[3] * wb3 + (float)a[4] * wb4 + (float)a[5] * wb5
                  + (float)a[6] * wb6 + (float)a[7] * wb7;
        float wsq = wb0 * wb0 + wb1 * wb1 + wb2 * wb2 + wb3 * wb3
                  + wb4 * wb4 + wb5 * wb5 + wb6 * wb6 + wb7 * wb7;
        #pragma unroll
        for (int o = 1; o < 64; o <<= 1) { dot += __shfl_xor(dot, o); wsq += __shfl_xor(wsq, o); }
        if (l == 0) {
            float cs = dot * rsqrtf(wsq);
            float sn = sqrtf(fmaxf(0.f, fminf(1.f, 1.f - cs * cs)));
            float phi = cs * COS_M - sn * SIN_M;
            if (!(cs > TH_C)) phi = cs - MM_C;
            sphi[row] = S_SCALE * phi;
            scos[row] = S_SCALE * cs;
        }
        return;
    }

    // ---------- W-prep: col-block cb, 128 cols, 4 waves x 32 cols ----------
    const int cb = blockIdx.x - 128;
    char* wtb = (char*)Wt + (size_t)cb * 16 * 8192;   // 16 tiles of [128][32] bf16
    for (int p = 0; p < 32; ++p) {
        const int c  = wave * 32 + p;                 // col within block
        const int gc = cb * 128 + c;                  // global col
        bf16x4 b0, b1;
        float sq = 0.f;
        if (gc < CC) {
            const float4* src = (const float4*)(W + (size_t)gc * DD);
            float4 f0 = src[l];          // k = l*4 .. l*4+3
            float4 f1 = src[64 + l];     // k = 256 + l*4 ..
            b0[0] = (__bf16)f0.x; b0[1] = (__bf16)f0.y;
            b0[2] = (__bf16)f0.z; b0[3] = (__bf16)f0.w;
            b1[0] = (__bf16)f1.x; b1[1] = (__bf16)f1.y;
            b1[2] = (__bf16)f1.z; b1[3] = (__bf16)f1.w;
            float f;
            f = (float)b0[0]; sq += f * f; f = (float)b0[1]; sq += f * f;
            f = (float)b0[2]; sq += f * f; f = (float)b0[3]; sq += f * f;
            f = (float)b1[0]; sq += f * f; f = (float)b1[1]; sq += f * f;
            f = (float)b1[2]; sq += f * f; f = (float)b1[3]; sq += f * f;
        } else {
            b0 = bf16x4{(__bf16)0.f, (__bf16)0.f, (__bf16)0.f, (__bf16)0.f};
            b1 = b0;
        }
        #pragma unroll
        for (int o = 1; o < 64; o <<= 1) sq += __shfl_xor(sq, o);
        // tile j = k>>5; within-tile byte = c*64 + (k&31)*2
        *(bf16x4*)(wtb + (size_t)(l >> 3) * 8192 + c * 64 + (l & 7) * 8) = b0;
        *(bf16x4*)(wtb + (size_t)(8 + (l >> 3)) * 8192 + c * 64 + (l & 7) * 8) = b1;
        if (l == 0) csqg[gc] = sq;
    }
}

// ---------------- Kernel 2: MFMA GEMM, pure m97 loop. 128 rows x 128 cols per
// 256-thread block; BOTH operands bf16 via global_load_lds (coalesced dwordx4);
// per K-step: barrier + 4 glds + 8 ds_read_b128 + 16 MFMA. Nothing else.
// LDS 32KB -> 3 blocks/CU. XOR chunk swizzle on glds SOURCE + frag reads. -------
__global__ __launch_bounds__(256, 3) void k_gemm(const __bf16* __restrict__ At,
                                                 const __bf16* __restrict__ Wt,
                                                 const float* __restrict__ csqg,
                                                 float* __restrict__ part) {
    __shared__ __bf16 As[2][128 * 32];   // 2 x 8 KB
    __shared__ __bf16 Bs[2][128 * 32];   // 2 x 8 KB

    const int t = threadIdx.x;
    const int bid = blockIdx.x;
    const int swz = (bid & 7) * 391 + (bid >> 3);   // 3128 = 8*391, bijective
    const int rb = swz & 3;                         // row block (128 rows)
    const int cb = swz >> 2;                        // col block (128 cols)
    const int wave = t >> 6, lane = t & 63, q = lane >> 4, m16 = lane & 15;
    const int wr = wave >> 1, wc = wave & 1;        // wave quadrant: 64r x 64c

    const int frag_off = m16 * 32 + ((q ^ ((m16 >> 1) & 3)) << 3);
    const int srcswz   = ((t >> 2) << 6) + ((((t & 3) ^ ((t >> 3) & 3))) << 4);

    const char* abase = (const char*)At + (size_t)rb * 8192 + srcswz;      // +kt*32768
    const char* bbase = (const char*)Wt + (size_t)cb * 131072 + srcswz;    // +kt*8192

    f32x4 acc[4][4] = {};

#define GLDS_A(kt, buf)                                                                 \
    {                                                                                   \
        _Pragma("unroll")                                                               \
        for (int rr = 0; rr < 2; ++rr)                                                  \
            __builtin_amdgcn_global_load_lds(                                           \
                (AS1 void*)(abase + (size_t)(kt) * 32768 + rr * 4096),                  \
                (AS3 void*)((char*)(&As[buf][0]) + rr * 4096 + wave * 1024),            \
                16, 0, 0);                                                              \
    }
#define GLDS_B(kt, buf)                                                                 \
    {                                                                                   \
        _Pragma("unroll")                                                               \
        for (int rr = 0; rr < 2; ++rr)                                                  \
            __builtin_amdgcn_global_load_lds(                                           \
                (AS1 void*)(bbase + (size_t)(kt) * 8192 + rr * 4096),                   \
                (AS3 void*)((char*)(&Bs[buf][0]) + rr * 4096 + wave * 1024),            \
                16, 0, 0);                                                              \
    }

    GLDS_A(0, 0);
    GLDS_B(0, 0);

    #pragma unroll
    for (int kt = 0; kt < 16; ++kt) {
        __syncthreads();                       // drains glds(kt); prev readers done
        if (kt < 15) {
            GLDS_A(kt + 1, (kt + 1) & 1);
            GLDS_B(kt + 1, (kt + 1) & 1);
        }
        bf16x8 bfrag[4], afrag[4];
        #pragma unroll
        for (int j = 0; j < 4; ++j)
            bfrag[j] = *(const bf16x8*)(&Bs[kt & 1][wc * 2048 + j * 512 + frag_off]);
        #pragma unroll
        for (int i = 0; i < 4; ++i)
            afrag[i] = *(const bf16x8*)(&As[kt & 1][wr * 2048 + i * 512 + frag_off]);
        #pragma unroll
        for (int i = 0; i < 4; ++i) {
            #pragma unroll
            for (int j = 0; j < 4; ++j)
                acc[i][j] = __builtin_amdgcn_mfma_f32_16x16x32_bf16(
                    afrag[i], bfrag[j], acc[i][j], 0, 0, 0);
        }
    }

    // epilogue: partial sum of exp(S * cosine) per row, per 64-col wave group
    const bool lastb = (cb == LASTB2);
    float inv[4]; bool val[4];
    #pragma unroll
    for (int j = 0; j < 4; ++j) {
        int ct = wc * 64 + j * 16 + m16;
        val[j] = (!lastb) || (ct < 32);        // last col-block: 32 valid cols
        inv[j] = rsqrtf(csqg[cb * 128 + ct]) * S_SCALE;
    }
    #pragma unroll
    for (int i = 0; i < 4; ++i) {
        #pragma unroll
        for (int r = 0; r < 4; ++r) {
            float e = 0.f;
            #pragma unroll
            for (int j = 0; j < 4; ++j)
                if (val[j]) e += __expf(acc[i][j][r] * inv[j]);
            e += __shfl_xor(e, 1);
            e += __shfl_xor(e, 2);
            e += __shfl_xor(e, 4);
            e += __shfl_xor(e, 8);
            if (m16 == 0)
                part[((size_t)cb * 2 + wc) * BD + rb * 128 + wr * 64 + i * 16 + q * 4 + r] = e;
        }
    }
#undef GLDS_A
#undef GLDS_B
}

// ---------------- Kernel 3 (merged): partial row-sums + last-block final LSE ----------
__global__ __launch_bounds__(256) void k_reduce(const float* __restrict__ part,
                                                const float* __restrict__ sphi,
                                                const float* __restrict__ scos,
                                                float* __restrict__ rowpart,
                                                int* __restrict__ cnt,
                                                float* __restrict__ out) {
    const int b = blockIdx.x;
    const int rg = b >> 5, cp = b & 31;
    const int t = threadIdx.x;
    const int rl = t & 63, ph = t >> 6;     // 4 phases
    const int r0 = rg * 64;
    float s = 0.f;
    for (int c0 = cp * 4 + ph; c0 < NPART; c0 += 128)
        s += part[(size_t)c0 * BD + r0 + rl];
    __shared__ float buf[256];
    buf[t] = s;
    __syncthreads();
    if (t < 64)
        rowpart[(size_t)cp * BD + r0 + t] = buf[t] + buf[t + 64] + buf[t + 128] + buf[t + 192];

    // ---- last-block final: ticket pattern ----
    __threadfence();
    __syncthreads();                         // all threads past their fence
    __shared__ int lastf;
    if (t == 0) lastf = (atomicAdd(cnt, 1) == 255) ? 1 : 0;
    __syncthreads();
    if (!lastf) return;
    __threadfence();                         // acquire other blocks' rowpart

    float a = 0.f;
    for (int r = t; r < BD; r += 256) {
        float total = 0.f;
        #pragma unroll
        for (int c = 0; c < 32; ++c)
            total += rowpart[(size_t)c * BD + r];
        float lse = logf(total);
        float sp = sphi[r], sc = scos[r];
        float corr = log1pf(__expf(sp - lse) - __expf(sc - lse));
        a += lse + corr - sp;
    }
    #pragma unroll
    for (int o = 1; o < 64; o <<= 1) a += __shfl_xor(a, o);
    __shared__ float wsum[4];
    if ((t & 63) == 0) wsum[t >> 6] = a;
    __syncthreads();
    if (t == 0) out[0] = (wsum[0] + wsum[1] + wsum[2] + wsum[3]) * (1.0f / 512.0f);
}

extern "C" void kernel_launch(void* const* d_in, const int* in_sizes, int n_in,
                              void* d_out, int out_size, void* d_ws, size_t ws_size,
                              hipStream_t stream) {
    const float* img  = (const float*)d_in[0];
    const float* prof = (const float*)d_in[1];
    const float* W    = (const float*)d_in[2];
    const int*   lab  = (const int*)d_in[3];

    char* ws = (char*)d_ws;
    __bf16* At     = (__bf16*)ws;                  // 524,288 B (k-tiled A)
    float* sphi    = (float*)(ws + 524288);        // 2 KB
    float* scos    = (float*)(ws + 526336);        // 2 KB
    float* part    = (float*)(ws + 528384);        // 1564*512*4 = 3,203,072 B
    float* rowpart = (float*)(ws + 3731456);       // 32*512*4 = 65,536 B
    float* csqg    = (float*)(ws + 3796992);       // 100096*4 = 400,384 B
    int*   cnt     = (int*)(ws + 4197376);         // ticket counter (reset by k_prep)
    __bf16* Wt     = (__bf16*)(ws + 4198400);      // 782*16*8192 = 102,498,304 B

    k_prep<<<910, 256, 0, stream>>>(img, prof, W, lab, At, sphi, scos, Wt, csqg, cnt);
    k_gemm<<<4 * NCB2, 256, 0, stream>>>(At, Wt, csqg, part);
    k_reduce<<<256, 256, 0, stream>>>(part, sphi, scos, rowpart, cnt, (float*)d_out);
}

// Round 7
// 402.566 us; speedup vs baseline: 1.0598x; 1.0598x over previous
//
#include <hip/hip_runtime.h>

#define S_SCALE 30.0f
#define COS_M 0.8775825618903728f
#define SIN_M 0.479425538604203f
#define TH_C (-0.8775825618903728f)
#define MM_C 0.2397127693021015f

#define BD 512
#define DD 512
#define CC 100000
#define NCB2 782            // ceil(100000/128) col-blocks
#define LASTB2 781
#define NPART 1564          // 782 col-blocks x 2 col-groups of 64
#define CPAD 100096         // padded col count (782*128)
#define NWB 12512           // CPAD/8 W-prep blocks

typedef __bf16 bf16x8 __attribute__((ext_vector_type(8)));
typedef __bf16 bf16x4 __attribute__((ext_vector_type(4)));
typedef float  f32x4  __attribute__((ext_vector_type(4)));

#define AS1 __attribute__((address_space(1)))
#define AS3 __attribute__((address_space(3)))

// ---------------- Kernel 1 (merged): blocks 0..127: A-prep (concat+normalize ->
// k-tiled bf16 At[16][512][32]) + label-column cosine/phi.
// Blocks 128..128+NWB-1: W -> ROW-MAJOR bf16 Wt[CPAD][512] + per-row sumsq csqg.
// Fully coalesced streaming: 16B/lane reads, 8B/lane writes, one 5-shfl reduce. ----
__global__ __launch_bounds__(256) void k_prep(const float* __restrict__ img,
                                              const float* __restrict__ prof,
                                              const float* __restrict__ W,
                                              const int* __restrict__ lab,
                                              __bf16* __restrict__ At,
                                              float* __restrict__ sphi,
                                              float* __restrict__ scos,
                                              __bf16* __restrict__ Wt,
                                              float* __restrict__ csqg,
                                              int* __restrict__ cnt) {
    const int t = threadIdx.x;

    if (blockIdx.x < 128) {
        // ---------- A-prep (one wave per row) ----------
        const int wave = t >> 6, l = t & 63;
        if (blockIdx.x == 0 && t == 0) cnt[0] = 0;   // reset ticket for k_reduce
        const int row = blockIdx.x * 4 + wave;
        const float* src = (row < 256) ? (img + (size_t)row * DD)
                                       : (prof + (size_t)(row - 256) * DD);
        float4 v0 = ((const float4*)src)[l * 2];
        float4 v1 = ((const float4*)src)[l * 2 + 1];
        float s = v0.x * v0.x + v0.y * v0.y + v0.z * v0.z + v0.w * v0.w
                + v1.x * v1.x + v1.y * v1.y + v1.z * v1.z + v1.w * v1.w;
        #pragma unroll
        for (int o = 1; o < 64; o <<= 1) s += __shfl_xor(s, o);
        float r = rsqrtf(s);
        bf16x8 a;
        a[0] = (__bf16)(v0.x * r); a[1] = (__bf16)(v0.y * r);
        a[2] = (__bf16)(v0.z * r); a[3] = (__bf16)(v0.w * r);
        a[4] = (__bf16)(v1.x * r); a[5] = (__bf16)(v1.y * r);
        a[6] = (__bf16)(v1.z * r); a[7] = (__bf16)(v1.w * r);
        // element (row, d) -> At[(d>>5)*16384 + row*32 + (d&31)]
        *(bf16x8*)(At + (size_t)(l >> 2) * (BD * 32) + row * 32 + (l & 3) * 8) = a;

        // label-column cosine (bf16-truncated, matching the GEMM)
        const int c = lab[row & 255];
        const float4* wc = (const float4*)(W + (size_t)c * DD);
        float4 w0 = wc[l * 2], w1 = wc[l * 2 + 1];
        float wb0 = (float)(__bf16)w0.x, wb1 = (float)(__bf16)w0.y;
        float wb2 = (float)(__bf16)w0.z, wb3 = (float)(__bf16)w0.w;
        float wb4 = (float)(__bf16)w1.x, wb5 = (float)(__bf16)w1.y;
        float wb6 = (float)(__bf16)w1.z, wb7 = (float)(__bf16)w1.w;
        float dot = (float)a[0] * wb0 + (float)a[1] * wb1 + (float)a[2] * wb2
                  + (float)a[3] * wb3 + (float)a[4] * wb4 + (float)a[5] * wb5
                  + (float)a[6] * wb6 + (float)a[7] * wb7;
        float wsq = wb0 * wb0 + wb1 * wb1 + wb2 * wb2 + wb3 * wb3
                  + wb4 * wb4 + wb5 * wb5 + wb6 * wb6 + wb7 * wb7;
        #pragma unroll
        for (int o = 1; o < 64; o <<= 1) { dot += __shfl_xor(dot, o); wsq += __shfl_xor(wsq, o); }
        if (l == 0) {
            float cs = dot * rsqrtf(wsq);
            float sn = sqrtf(fmaxf(0.f, fminf(1.f, 1.f - cs * cs)));
            float phi = cs * COS_M - sn * SIN_M;
            if (!(cs > TH_C)) phi = cs - MM_C;
            sphi[row] = S_SCALE * phi;
            scos[row] = S_SCALE * cs;
        }
        return;
    }

    // ---------- W-prep: 8 rows per block, 32 lanes per row, streaming cast ----------
    const int wb  = blockIdx.x - 128;          // 0..NWB-1
    const int row = wb * 8 + (t >> 5);         // W row = gemm column, 0..CPAD-1
    const int g   = t & 31;
    float sq = 0.f;
    bf16x4 ob[4];
    if (row < CC) {
        const float4* src = (const float4*)(W + (size_t)row * DD);
        #pragma unroll
        for (int i = 0; i < 4; ++i) {
            float4 v = src[g + 32 * i];
            bf16x4 b;
            b[0] = (__bf16)v.x; b[1] = (__bf16)v.y;
            b[2] = (__bf16)v.z; b[3] = (__bf16)v.w;
            float f;
            f = (float)b[0]; sq += f * f; f = (float)b[1]; sq += f * f;
            f = (float)b[2]; sq += f * f; f = (float)b[3]; sq += f * f;
            ob[i] = b;
        }
    } else {
        #pragma unroll
        for (int i = 0; i < 4; ++i)
            ob[i] = bf16x4{(__bf16)0.f, (__bf16)0.f, (__bf16)0.f, (__bf16)0.f};
    }
    #pragma unroll
    for (int o = 1; o < 32; o <<= 1) sq += __shfl_xor(sq, o);
    bf16x4* dst = (bf16x4*)(Wt + (size_t)row * DD);
    #pragma unroll
    for (int i = 0; i < 4; ++i) dst[g + 32 * i] = ob[i];
    if (g == 0) csqg[row] = (row < CC) ? sq : 1.0f;
}

// ---------------- Kernel 2: MFMA GEMM, 256 rows x 128 cols per 256-thread block.
// A: linear glds from k-tiled At. B: per-lane-GATHER glds from row-major bf16 Wt
// (source addr carries k-tiling + XOR swizzle; LDS linear -> rule 21 satisfied).
// m97 loop: barrier + 6 glds + 12 ds_read + 32 MFMA per K-step. LDS 48 KB. -------
__global__ __launch_bounds__(256, 2) void k_gemm(const __bf16* __restrict__ At,
                                                 const __bf16* __restrict__ Wt,
                                                 const float* __restrict__ csqg,
                                                 float* __restrict__ part) {
    __shared__ __bf16 As[2][256 * 32];   // 2 x 16 KB
    __shared__ __bf16 Bs[2][128 * 32];   // 2 x 8 KB

    const int t = threadIdx.x;
    const int bid = blockIdx.x;          // 1564 blocks
    const int rb = bid & 1;              // row block (256 rows)
    const int cb = bid >> 1;             // col block (128 cols), 0..781
    const int wave = t >> 6, lane = t & 63, q = lane >> 4, m16 = lane & 15;
    const int wr = wave >> 1, wc = wave & 1;   // wave quadrant: 128r x 64c

    const int frag_off = m16 * 32 + ((q ^ ((m16 >> 1) & 3)) << 3);
    // A glds source pre-swizzle (bytes): row t>>2, chunk (t&3)^((row>>1)&3)
    const int srcswz = ((t >> 2) << 6) + ((((t & 3) ^ ((t >> 3) & 3))) << 4);
    const char* abase = (const char*)At + (size_t)rb * 16384 + srcswz;   // +kt*32768+p*4096

    // B gather source: thread t -> local col bcol=t>>2 (and +64), stored chunk bs=t&3;
    // stored chunk bs of col c holds source k-chunk bs ^ ((c>>1)&3)
    const int bcol = t >> 2, bs = t & 3;
    const int bswz = (bs ^ ((bcol >> 1) & 3)) << 4;     // same for bcol and bcol+64
    const char* bsrc0 = (const char*)Wt + (size_t)(cb * 128 + bcol) * 1024 + bswz;
    const char* bsrc1 = (const char*)Wt + (size_t)(cb * 128 + 64 + bcol) * 1024 + bswz;

    f32x4 acc[8][4] = {};

#define GLDS_A(kt, buf)                                                                 \
    {                                                                                   \
        _Pragma("unroll")                                                               \
        for (int p = 0; p < 4; ++p)                                                     \
            __builtin_amdgcn_global_load_lds(                                           \
                (AS1 void*)(abase + (size_t)(kt) * 32768 + p * 4096),                   \
                (AS3 void*)((char*)(&As[buf][0]) + p * 4096 + wave * 1024),             \
                16, 0, 0);                                                              \
    }
#define GLDS_B(kt, buf)                                                                 \
    {                                                                                   \
        __builtin_amdgcn_global_load_lds(                                               \
            (AS1 void*)(bsrc0 + (kt) * 64),                                             \
            (AS3 void*)((char*)(&Bs[buf][0]) + wave * 1024), 16, 0, 0);                 \
        __builtin_amdgcn_global_load_lds(                                               \
            (AS1 void*)(bsrc1 + (kt) * 64),                                             \
            (AS3 void*)((char*)(&Bs[buf][0]) + 4096 + wave * 1024), 16, 0, 0);          \
    }

    GLDS_A(0, 0);
    GLDS_B(0, 0);

    #pragma unroll
    for (int kt = 0; kt < 16; ++kt) {
        __syncthreads();                       // drains glds(kt); prev readers done
        if (kt < 15) {
            GLDS_A(kt + 1, (kt + 1) & 1);
            GLDS_B(kt + 1, (kt + 1) & 1);
        }
        bf16x8 bfrag[4], afrag[8];
        #pragma unroll
        for (int j = 0; j < 4; ++j)
            bfrag[j] = *(const bf16x8*)(&Bs[kt & 1][wc * 2048 + j * 512 + frag_off]);
        #pragma unroll
        for (int i = 0; i < 8; ++i)
            afrag[i] = *(const bf16x8*)(&As[kt & 1][wr * 4096 + i * 512 + frag_off]);
        #pragma unroll
        for (int i = 0; i < 8; ++i) {
            #pragma unroll
            for (int j = 0; j < 4; ++j)
                acc[i][j] = __builtin_amdgcn_mfma_f32_16x16x32_bf16(
                    afrag[i], bfrag[j], acc[i][j], 0, 0, 0);
        }
    }

    // epilogue: partial sum of exp(S * cosine) per row, per 64-col wave group
    const bool lastb = (cb == LASTB2);
    float inv[4]; bool val[4];
    #pragma unroll
    for (int j = 0; j < 4; ++j) {
        int ct = wc * 64 + j * 16 + m16;
        val[j] = (!lastb) || (ct < 32);        // last col-block: 32 valid cols
        inv[j] = rsqrtf(csqg[cb * 128 + ct]) * S_SCALE;
    }
    #pragma unroll
    for (int i = 0; i < 8; ++i) {
        #pragma unroll
        for (int r = 0; r < 4; ++r) {
            float e = 0.f;
            #pragma unroll
            for (int j = 0; j < 4; ++j)
                if (val[j]) e += __expf(acc[i][j][r] * inv[j]);
            e += __shfl_xor(e, 1);
            e += __shfl_xor(e, 2);
            e += __shfl_xor(e, 4);
            e += __shfl_xor(e, 8);
            if (m16 == 0)
                part[((size_t)cb * 2 + wc) * BD + rb * 256 + wr * 128 + i * 16 + q * 4 + r] = e;
        }
    }
#undef GLDS_A
#undef GLDS_B
}

// ---------------- Kernel 3 (merged): partial row-sums + last-block final LSE ----------
__global__ __launch_bounds__(256) void k_reduce(const float* __restrict__ part,
                                                const float* __restrict__ sphi,
                                                const float* __restrict__ scos,
                                                float* __restrict__ rowpart,
                                                int* __restrict__ cnt,
                                                float* __restrict__ out) {
    const int b = blockIdx.x;
    const int rg = b >> 5, cp = b & 31;
    const int t = threadIdx.x;
    const int rl = t & 63, ph = t >> 6;     // 4 phases
    const int r0 = rg * 64;
    float s = 0.f;
    for (int c0 = cp * 4 + ph; c0 < NPART; c0 += 128)
        s += part[(size_t)c0 * BD + r0 + rl];
    __shared__ float buf[256];
    buf[t] = s;
    __syncthreads();
    if (t < 64)
        rowpart[(size_t)cp * BD + r0 + t] = buf[t] + buf[t + 64] + buf[t + 128] + buf[t + 192];

    // ---- last-block final: ticket pattern ----
    __threadfence();
    __syncthreads();
    __shared__ int lastf;
    if (t == 0) lastf = (atomicAdd(cnt, 1) == 255) ? 1 : 0;
    __syncthreads();
    if (!lastf) return;
    __threadfence();

    float a = 0.f;
    for (int r = t; r < BD; r += 256) {
        float total = 0.f;
        #pragma unroll
        for (int c = 0; c < 32; ++c)
            total += rowpart[(size_t)c * BD + r];
        float lse = logf(total);
        float sp = sphi[r], sc = scos[r];
        float corr = log1pf(__expf(sp - lse) - __expf(sc - lse));
        a += lse + corr - sp;
    }
    #pragma unroll
    for (int o = 1; o < 64; o <<= 1) a += __shfl_xor(a, o);
    __shared__ float wsum[4];
    if ((t & 63) == 0) wsum[t >> 6] = a;
    __syncthreads();
    if (t == 0) out[0] = (wsum[0] + wsum[1] + wsum[2] + wsum[3]) * (1.0f / 512.0f);
}

extern "C" void kernel_launch(void* const* d_in, const int* in_sizes, int n_in,
                              void* d_out, int out_size, void* d_ws, size_t ws_size,
                              hipStream_t stream) {
    const float* img  = (const float*)d_in[0];
    const float* prof = (const float*)d_in[1];
    const float* W    = (const float*)d_in[2];
    const int*   lab  = (const int*)d_in[3];

    char* ws = (char*)d_ws;
    __bf16* At     = (__bf16*)ws;                  // 524,288 B (k-tiled A)
    float* sphi    = (float*)(ws + 524288);        // 2 KB
    float* scos    = (float*)(ws + 526336);        // 2 KB
    float* part    = (float*)(ws + 528384);        // 1564*512*4 = 3,203,072 B
    float* rowpart = (float*)(ws + 3731456);       // 32*512*4 = 65,536 B
    float* csqg    = (float*)(ws + 3796992);       // 100096*4 = 400,384 B
    int*   cnt     = (int*)(ws + 4197376);         // ticket counter (reset by k_prep)
    __bf16* Wt     = (__bf16*)(ws + 4198400);      // 100096*512*2 = 102,498,304 B (row-major)

    k_prep<<<128 + NWB, 256, 0, stream>>>(img, prof, W, lab, At, sphi, scos, Wt, csqg, cnt);
    k_gemm<<<2 * NCB2, 256, 0, stream>>>(At, Wt, csqg, part);
    k_reduce<<<256, 256, 0, stream>>>(part, sphi, scos, rowpart, cnt, (float*)d_out);
}